// Round 4
// baseline (860.572 us; speedup 1.0000x reference)
//
#include <hip/hip_runtime.h>

typedef int v4i __attribute__((ext_vector_type(4)));

__global__ __launch_bounds__(256) void marble_wander_kernel(
    const float* __restrict__ x,
    const int*   __restrict__ paths,   // [n][16] int32
    const float* __restrict__ weights, // [2^21] floats, 8 MB
    float*       __restrict__ out,
    int n)
{
    int i = blockIdx.x * blockDim.x + threadIdx.x;
    bool valid = (i < n);
    int ii = valid ? i : 0;

    // 16 path indices = 64 contiguous bytes -> 4x 16B nt vector loads (streamed
    // once; keep them from evicting hot weight lines in L2).
    const v4i* p = reinterpret_cast<const v4i*>(paths) + (size_t)ii * 4;
    v4i p0 = __builtin_nontemporal_load(p + 0);
    v4i p1 = __builtin_nontemporal_load(p + 1);
    v4i p2 = __builtin_nontemporal_load(p + 2);
    v4i p3 = __builtin_nontemporal_load(p + 3);

    unsigned idx[16] = { (unsigned)p0.x, (unsigned)p0.y, (unsigned)p0.z, (unsigned)p0.w,
                         (unsigned)p1.x, (unsigned)p1.y, (unsigned)p1.z, (unsigned)p1.w,
                         (unsigned)p2.x, (unsigned)p2.y, (unsigned)p2.z, (unsigned)p2.w,
                         (unsigned)p3.x, (unsigned)p3.y, (unsigned)p3.z, (unsigned)p3.w };

    // Batcher odd-even merge sort, 16 elements, 63 compare-exchanges.
    // Product is commutative: sorting only creates gather locality (step j
    // across all waves targets quantile j/16 of the table, ~1 MB window ->
    // L2-resident), it cannot affect the result.
    #define CE(a,b) { unsigned lo_ = min(idx[a], idx[b]); \
                      unsigned hi_ = max(idx[a], idx[b]); \
                      idx[a] = lo_; idx[b] = hi_; }
    CE(0,1)  CE(2,3)  CE(4,5)  CE(6,7)  CE(8,9)  CE(10,11) CE(12,13) CE(14,15)
    CE(0,2)  CE(1,3)  CE(4,6)  CE(5,7)  CE(8,10) CE(9,11)  CE(12,14) CE(13,15)
    CE(1,2)  CE(5,6)  CE(9,10) CE(13,14)
    CE(0,4)  CE(1,5)  CE(2,6)  CE(3,7)  CE(8,12) CE(9,13)  CE(10,14) CE(11,15)
    CE(2,4)  CE(3,5)  CE(10,12) CE(11,13)
    CE(1,2)  CE(3,4)  CE(5,6)  CE(9,10) CE(11,12) CE(13,14)
    CE(0,8)  CE(1,9)  CE(2,10) CE(3,11) CE(4,12) CE(5,13)  CE(6,14)  CE(7,15)
    CE(4,8)  CE(5,9)  CE(6,10) CE(7,11)
    CE(2,4)  CE(3,5)  CE(6,8)  CE(7,9)  CE(10,12) CE(11,13)
    CE(1,2)  CE(3,4)  CE(5,6)  CE(7,8)  CE(9,10) CE(11,12) CE(13,14)
    #undef CE

    // 16 unpredicated gathers, all issued before any use -> 16 lines in
    // flight per wave, 0 branches, 0 barriers. L2-cacheable (no nt!) so the
    // quantile window stays resident.
    float w[16];
    #pragma unroll
    for (int j = 0; j < 16; ++j) w[j] = weights[idx[j]];

    float a0 = w[0]  * w[1];
    float a1 = w[2]  * w[3];
    float a2 = w[4]  * w[5];
    float a3 = w[6]  * w[7];
    float a4 = w[8]  * w[9];
    float a5 = w[10] * w[11];
    float a6 = w[12] * w[13];
    float a7 = w[14] * w[15];
    float b0 = a0 * a1;
    float b1 = a2 * a3;
    float b2 = a4 * a5;
    float b3 = a6 * a7;
    float prod = (b0 * b1) * (b2 * b3);

    float xv = __builtin_nontemporal_load(&x[ii]);
    float r  = xv * prod;
    if (valid) __builtin_nontemporal_store(r, &out[i]);
}

extern "C" void kernel_launch(void* const* d_in, const int* in_sizes, int n_in,
                              void* d_out, int out_size, void* d_ws, size_t ws_size,
                              hipStream_t stream) {
    const float* x       = (const float*)d_in[0];
    const int*   paths   = (const int*)d_in[1];
    const float* weights = (const float*)d_in[2];
    float*       out     = (float*)d_out;

    int n = in_sizes[0]; // 2048*2048 = 4194304
    int block = 256;
    int grid = (n + block - 1) / block;
    marble_wander_kernel<<<grid, block, 0, stream>>>(x, paths, weights, out, n);
}

// Round 5
// 834.298 us; speedup vs baseline: 1.0315x; 1.0315x over previous
//
#include <hip/hip_runtime.h>

typedef int v4i __attribute__((ext_vector_type(4)));

#define LOG2_CHUNK 19   // 2^19 floats = 2 MB window (fits 4 MB per-XCD L2)
#define NCHUNK 4        // 2^21 / 2^19

__global__ __launch_bounds__(256) void marble_wander_kernel(
    const float* __restrict__ x,
    const int*   __restrict__ paths,   // [n][16] int32
    const float* __restrict__ weights, // [2^21] floats, 8 MB
    float*       __restrict__ out,
    int n)
{
    int i = blockIdx.x * blockDim.x + threadIdx.x;
    bool valid = (i < n);
    int ii = valid ? i : 0;

    // 16 path indices = 64 contiguous bytes -> 4x 16B nt vector loads
    // (streamed once; don't evict hot weight lines from L2).
    const v4i* p = reinterpret_cast<const v4i*>(paths) + (size_t)ii * 4;
    v4i p0 = __builtin_nontemporal_load(p + 0);
    v4i p1 = __builtin_nontemporal_load(p + 1);
    v4i p2 = __builtin_nontemporal_load(p + 2);
    v4i p3 = __builtin_nontemporal_load(p + 3);

    unsigned idx[16] = { (unsigned)p0.x, (unsigned)p0.y, (unsigned)p0.z, (unsigned)p0.w,
                         (unsigned)p1.x, (unsigned)p1.y, (unsigned)p1.z, (unsigned)p1.w,
                         (unsigned)p2.x, (unsigned)p2.y, (unsigned)p2.z, (unsigned)p2.w,
                         (unsigned)p3.x, (unsigned)p3.y, (unsigned)p3.z, (unsigned)p3.w };

    float acc0 = 1.0f, acc1 = 1.0f, acc2 = 1.0f, acc3 = 1.0f;

    // Phased gather over 4x 2MB L2-resident windows (product is commutative).
    // Branch-free: out-of-window lanes load a dummy in-window broadcast line
    // and contribute 1.0f. All 16 loads of a phase are independent and
    // unpredicated -> issued as a batch, one waitcnt, no exec-mask regions.
    #pragma unroll
    for (int c = 0; c < NCHUNK; ++c) {
        unsigned base = (unsigned)c << LOG2_CHUNK;
        float wv[16];
        bool  in[16];
        #pragma unroll
        for (int j = 0; j < 16; ++j) {
            in[j] = (idx[j] >> LOG2_CHUNK) == (unsigned)c;
            unsigned a = in[j] ? idx[j] : base;   // dummy = 1 broadcast line
            wv[j] = weights[a];
        }
        #pragma unroll
        for (int j = 0; j < 16; ++j) {
            float f = in[j] ? wv[j] : 1.0f;
            if      ((j & 3) == 0) acc0 *= f;
            else if ((j & 3) == 1) acc1 *= f;
            else if ((j & 3) == 2) acc2 *= f;
            else                   acc3 *= f;
        }
        // Phase fence: drains vmcnt, bounds the in-flight footprint to one
        // window (R4 proved all-windows-in-flight thrashes L2).
        __syncthreads();
    }

    float xv = __builtin_nontemporal_load(&x[ii]);
    float r  = xv * ((acc0 * acc1) * (acc2 * acc3));
    if (valid) __builtin_nontemporal_store(r, &out[i]);
}

extern "C" void kernel_launch(void* const* d_in, const int* in_sizes, int n_in,
                              void* d_out, int out_size, void* d_ws, size_t ws_size,
                              hipStream_t stream) {
    const float* x       = (const float*)d_in[0];
    const int*   paths   = (const int*)d_in[1];
    const float* weights = (const float*)d_in[2];
    float*       out     = (float*)d_out;

    int n = in_sizes[0]; // 2048*2048 = 4194304
    int block = 256;
    int grid = (n + block - 1) / block;
    marble_wander_kernel<<<grid, block, 0, stream>>>(x, paths, weights, out, n);
}